// Round 1
// baseline (426.039 us; speedup 1.0000x reference)
//
#include <hip/hip_runtime.h>
#include <hip/hip_bf16.h>

using int32x4 = __attribute__((ext_vector_type(4))) int;

#define BM 256
#define BN 256
#define BKB 128  // K-bytes per tile = 2 x mfma_i32_16x16x64_i8 deep

// counted vmcnt gate (immediate); "memory" clobber pins LDS reads/stages
#define GATE(n) asm volatile("s_waitcnt vmcnt(" #n ")" ::: "memory")

// ---------------------------------------------------------------------------
// async 16B global->LDS (wave-uniform LDS base + lane*16; global addr per-lane)
__device__ __forceinline__ void load_lds16(const void* g, void* l) {
    __builtin_amdgcn_global_load_lds(
        (const __attribute__((address_space(1))) unsigned int*)g,
        (__attribute__((address_space(3))) unsigned int*)l, 16, 0, 0);
}

// ---------------------------------------------------------------------------
// Kernel 1: quantize activations to signed int8 (xq - a_zp) and per-row sums.
// Exact fp32 division + rintf matches numpy round-half-even.
__global__ __launch_bounds__(256) void quant_rows(
    const float* __restrict__ x, const float* __restrict__ act_scale,
    const int* __restrict__ act_zp, char* __restrict__ xs,
    int* __restrict__ rowsum, int K)
{
    __shared__ int wsum[4];
    const int row = blockIdx.x;
    const float s = act_scale[0];
    const int zp = act_zp[0];
    const float4* __restrict__ xr = (const float4*)(x + (size_t)row * K);
    char4* __restrict__ xo = (char4*)(xs + (size_t)row * K);
    const int nv = K >> 2;
    int sum = 0;
    for (int i = threadIdx.x; i < nv; i += 256) {
        float4 v = xr[i];
        int q0 = min(max((int)rintf(v.x / s) + zp, 0), 255) - zp;
        int q1 = min(max((int)rintf(v.y / s) + zp, 0), 255) - zp;
        int q2 = min(max((int)rintf(v.z / s) + zp, 0), 255) - zp;
        int q3 = min(max((int)rintf(v.w / s) + zp, 0), 255) - zp;
        sum += q0 + q1 + q2 + q3;
        char4 c;
        c.x = (char)q0; c.y = (char)q1; c.z = (char)q2; c.w = (char)q3;
        xo[i] = c;
    }
    for (int off = 32; off > 0; off >>= 1) sum += __shfl_down(sum, off, 64);
    if ((threadIdx.x & 63) == 0) wsum[threadIdx.x >> 6] = sum;
    __syncthreads();
    if (threadIdx.x == 0) rowsum[row] = wsum[0] + wsum[1] + wsum[2] + wsum[3];
}

// ---------------------------------------------------------------------------
// Kernel 2: weight int32 [N][K] -> int8 (w - 128)
__global__ __launch_bounds__(256) void wconv(
    const int4* __restrict__ wq, char4* __restrict__ wsq, long n4)
{
    long i = (long)blockIdx.x * 256 + threadIdx.x;
    if (i >= n4) return;
    int4 v = wq[i];
    char4 c;
    c.x = (char)(v.x - 128); c.y = (char)(v.y - 128);
    c.z = (char)(v.z - 128); c.w = (char)(v.w - 128);
    wsq[i] = c;
}

// ---------------------------------------------------------------------------
// Kernel 3: alpha[n] = a_s*w_s[n];  beta[n] = alpha[n]*(128-w_zp[n])
__global__ __launch_bounds__(256) void mkscales(
    const float* __restrict__ wscale, const int* __restrict__ wzp,
    const float* __restrict__ act_scale, float* __restrict__ alpha,
    float* __restrict__ beta, int N)
{
    int n = blockIdx.x * 256 + threadIdx.x;
    if (n >= N) return;
    float a = act_scale[0] * wscale[n];
    alpha[n] = a;
    beta[n] = a * (float)(128 - wzp[n]);
}

// ---------------------------------------------------------------------------
// Kernel 4: int8 GEMM, 256x256 tile, 8 waves (2M x 4N), BK=128 B, deep pipeline.
//
// Schedule (T3+T4+T5 port of the 256^2 8-phase template, i8 flavor):
//   K-tile = 128 B. 4 phases per K-tile, 16 MFMA each (2 M-frags x 4 N-frags
//   x 2 k-slices). Double-buffered LDS slots (2 x 64 KiB). Per phase, each
//   thread issues ONE staging unit share (2 x global_load_lds, 16 B) of the
//   NEXT tile. Unit issue order:  p0: B[0:128)  p1: B[128:256)
//   p2: A{[0,64)u[128,192)}      p3: A{[64,128)u[192,256)}.
//   Phase p consumes A rows wm + 32p .. +31 (in the unit staged one-tile-ago
//   at p2/p3) and, at p0 only, the full B quadrant (units from p0/p1).
//   Gates (counted, never 0 mid-loop):
//     p0: vmcnt(2)  -> forces B0,B1,A01 of current tile landed (leaves A23)
//     p2: vmcnt(4)  -> forces A23 of current tile landed (leaves next B0,B1)
//   Last tile peeled via uniform branch: p2 gate = vmcnt(0).
//   Raw s_barrier per phase (NOT __syncthreads: must not drain vmcnt).
//   lgkmcnt(0)+sched_barrier(0) before MFMA cluster (rule #18), setprio(1)
//   around MFMAs (T5).
//
// LDS swizzle (conflict-free ds_read_b128), same scheme as proven kernel:
// physical 16B chunk (row, pc) holds logical k-chunk c = pc ^ (row & 7);
// staging applies the swizzle on the per-lane GLOBAL source (row base always
// multiple of 8, so c = (lane&7) ^ (lane>>3)); readers XOR with (r&7).
__global__ __launch_bounds__(512, 2) void gemm_i8(
    const char* __restrict__ Aq, const char* __restrict__ Bq,
    const int* __restrict__ rowsum, const float* __restrict__ alpha,
    const float* __restrict__ beta, const float* __restrict__ bias,
    float* __restrict__ C, int M, int N, int K)
{
    __shared__ __align__(16) char As[2][BM * BKB];  // 2 x 32 KiB
    __shared__ __align__(16) char Bs[2][BN * BKB];  // 2 x 32 KiB

    const int tid = threadIdx.x;
    const int w   = tid >> 6;
    const int l   = tid & 63;

    // T1: bijective XCD swizzle (m204) — contiguous wg chunks per XCD
    const int nwg = gridDim.x;
    const int nbx = N / BN;
    const int orig = blockIdx.x;
    const int xcd = orig & 7;
    const int rest = orig >> 3;
    const int qq = nwg >> 3, rr = nwg & 7;
    const int wg = (xcd < rr ? xcd * (qq + 1) : rr * (qq + 1) + (xcd - rr) * qq)
                   + rest;
    const int n0 = (wg % nbx) * BN;
    const int m0 = (wg / nbx) * BM;

    const int wm = (w & 1) * 128;   // wave m-offset in tile
    const int wn = (w >> 1) * 64;   // wave n-offset in tile

    // ---- staging source (per-lane, pre-swizzled) + LDS unit bases (uniform)
    const int lr8 = l >> 3;
    const int csw = (((l & 7) ^ (lr8 & 7)) << 4);
    const int rB0 = w * 16;                                     // B-unit rows
    const int rA2 = (w < 4) ? (w * 16) : (128 + (w - 4) * 16);  // A01 rows

    const char* sB0 = Bq + (size_t)(n0 + rB0 + lr8) * K + csw;
    const char* sB1 = sB0 + (size_t)128 * K;
    const char* sA2 = Aq + (size_t)(m0 + rA2 + lr8) * K + csw;
    const char* sA3 = sA2 + (size_t)64 * K;
    const size_t k8 = (size_t)8 * K;

    const int oB0 = rB0 * BKB;
    const int oB1 = oB0 + 128 * BKB;
    const int oA2 = rA2 * BKB;
    const int oA3 = oA2 + 64 * BKB;

    // ---- fragment read offsets ----
    const int r   = l & 15;       // row within 16-tile (A: m, B: n)
    const int qk  = l >> 4;       // 16B k-quadrant within 64B k-slice
    const int rx  = r & 7;        // swizzle key
    const int rof = r * BKB;
    const int ck0 = ((qk ^ rx) << 4);
    const int ck1 = (((4 + qk) ^ rx) << 4);

    int32x4 acc[8][4] = {};
    const int NT = K / BKB;

    // prologue: stage tile 0 -> slot 0, unit order B0,B1,A01,A23 (no wait —
    // the steady-state gates inside the loop cover it)
    load_lds16(sB0,      Bs[0] + oB0);
    load_lds16(sB0 + k8, Bs[0] + oB0 + 1024);
    load_lds16(sB1,      Bs[0] + oB1);
    load_lds16(sB1 + k8, Bs[0] + oB1 + 1024);
    load_lds16(sA2,      As[0] + oA2);
    load_lds16(sA2 + k8, As[0] + oA2 + 1024);
    load_lds16(sA3,      As[0] + oA3);
    load_lds16(sA3 + k8, As[0] + oA3 + 1024);
    sB0 += BKB; sB1 += BKB; sA2 += BKB; sA3 += BKB;

    int s = 0;
    for (int T = 0; T < NT; ++T) {
        const char* cA = As[s];
        const char* cB = Bs[s];
        char* nA = As[s ^ 1];
        char* nB = Bs[s ^ 1];
        const bool stage = (T + 1 < NT);
        int32x4 bf[4][2];
#pragma unroll
        for (int p = 0; p < 4; ++p) {
            // gates BEFORE the barrier: every wave passes its own counted
            // wait, then the barrier makes that a block-wide guarantee.
            if (p == 0) { GATE(2); }
            if (p == 2) { if (stage) { GATE(4); } else { GATE(0); } }
            __builtin_amdgcn_s_barrier();

            // ds-reads for this phase (slot s; staging goes to slot s^1)
            int32x4 af[2][2];
            const char* ab = cA + (wm + p * 32) * BKB + rof;
            af[0][0] = *(const int32x4*)(ab + ck0);
            af[0][1] = *(const int32x4*)(ab + ck1);
            af[1][0] = *(const int32x4*)(ab + 2048 + ck0);
            af[1][1] = *(const int32x4*)(ab + 2048 + ck1);
            if (p == 0) {
                const char* bb = cB + wn * BKB + rof;
#pragma unroll
                for (int j = 0; j < 4; ++j) {
                    bf[j][0] = *(const int32x4*)(bb + j * 2048 + ck0);
                    bf[j][1] = *(const int32x4*)(bb + j * 2048 + ck1);
                }
            }
            // issue this phase's staging unit of tile T+1
            if (stage) {
                if (p == 0) { load_lds16(sB0, nB + oB0);
                              load_lds16(sB0 + k8, nB + oB0 + 1024); }
                if (p == 1) { load_lds16(sB1, nB + oB1);
                              load_lds16(sB1 + k8, nB + oB1 + 1024); }
                if (p == 2) { load_lds16(sA2, nA + oA2);
                              load_lds16(sA2 + k8, nA + oA2 + 1024); }
                if (p == 3) { load_lds16(sA3, nA + oA3);
                              load_lds16(sA3 + k8, nA + oA3 + 1024); }
            }
            asm volatile("s_waitcnt lgkmcnt(0)" ::: "memory");
            __builtin_amdgcn_sched_barrier(0);
            __builtin_amdgcn_s_setprio(1);
#pragma unroll
            for (int i = 0; i < 2; ++i)
#pragma unroll
                for (int j = 0; j < 4; ++j) {
                    acc[p * 2 + i][j] = __builtin_amdgcn_mfma_i32_16x16x64_i8(
                        af[i][0], bf[j][0], acc[p * 2 + i][j], 0, 0, 0);
                    acc[p * 2 + i][j] = __builtin_amdgcn_mfma_i32_16x16x64_i8(
                        af[i][1], bf[j][1], acc[p * 2 + i][j], 0, 0, 0);
                }
            __builtin_amdgcn_s_setprio(0);
        }
        sB0 += BKB; sB1 += BKB; sA2 += BKB; sA3 += BKB;
        s ^= 1;
    }

    // epilogue: C/D layout col=lane&15, row=(lane>>4)*4+reg
    const int r4  = qk * 4;
    const int cil = r;
#pragma unroll
    for (int j = 0; j < 4; ++j) {
        const int col = n0 + wn + j * 16 + cil;
        const float al = alpha[col];
        const float be = beta[col];
        const float bi = bias[col];
#pragma unroll
        for (int mi = 0; mi < 8; ++mi) {
            const int rowb = m0 + wm + mi * 16 + r4;
#pragma unroll
            for (int t = 0; t < 4; ++t) {
                const int row = rowb + t;
                C[(size_t)row * N + col] =
                    al * (float)acc[mi][j][t] + be * (float)rowsum[row] + bi;
            }
        }
    }
}

// ---------------------------------------------------------------------------
extern "C" void kernel_launch(void* const* d_in, const int* in_sizes, int n_in,
                              void* d_out, int out_size, void* d_ws, size_t ws_size,
                              hipStream_t stream) {
    const float* x      = (const float*)d_in[0];
    const int*   wq     = (const int*)d_in[1];
    const float* wscale = (const float*)d_in[2];
    const int*   wzp    = (const int*)d_in[3];
    const float* ascale = (const float*)d_in[4];
    const int*   azp    = (const int*)d_in[5];
    const float* bias   = (const float*)d_in[6];
    float* out = (float*)d_out;

    const int N = in_sizes[2];          // OUT
    const int K = in_sizes[1] / N;      // IN
    const int M = in_sizes[0] / K;      // B*S

    char* ws     = (char*)d_ws;
    char* xs     = ws;                                 // M*K int8
    char* wsq    = ws + (size_t)M * K;                 // N*K int8
    int*  rowsum = (int*)(wsq + (size_t)N * K);        // M int32
    float* alpha = (float*)((char*)rowsum + (size_t)M * 4);
    float* beta  = (float*)((char*)alpha + (size_t)N * 4);

    quant_rows<<<M, 256, 0, stream>>>(x, ascale, azp, xs, rowsum, K);

    long n4 = (long)N * K / 4;
    wconv<<<(int)((n4 + 255) / 256), 256, 0, stream>>>(
        (const int4*)wq, (char4*)wsq, n4);

    mkscales<<<(N + 255) / 256, 256, 0, stream>>>(wscale, wzp, ascale, alpha, beta, N);

    dim3 grid((M / BM) * (N / BN));
    gemm_i8<<<grid, 512, 0, stream>>>(xs, wsq, rowsum, alpha, beta, bias, out, M, N, K);
}

// Round 2
// 413.929 us; speedup vs baseline: 1.0293x; 1.0293x over previous
//
#include <hip/hip_runtime.h>
#include <hip/hip_bf16.h>

using int32x4 = __attribute__((ext_vector_type(4))) int;

#define BM 256
#define BN 256
#define BKB 128  // K-bytes per tile = 2 x mfma_i32_16x16x64_i8 deep

// counted vmcnt gate (immediate); "memory" clobber pins LDS reads/stages
#define GATE(n) asm volatile("s_waitcnt vmcnt(" #n ")" ::: "memory")

// ---------------------------------------------------------------------------
// async 16B global->LDS (wave-uniform LDS base + lane*16; global addr per-lane)
__device__ __forceinline__ void load_lds16(const void* g, void* l) {
    __builtin_amdgcn_global_load_lds(
        (const __attribute__((address_space(1))) unsigned int*)g,
        (__attribute__((address_space(3))) unsigned int*)l, 16, 0, 0);
}

// ---------------------------------------------------------------------------
// Kernel 1 (fused prep): blocks [0,M) quantize activation rows to signed int8
// (xq - a_zp) + per-row sums; blocks [M, M+WB) convert weights int32 -> int8
// (w - 128). Fusing removes one dispatch's serialization bubble and lets the
// two independent streams overlap.
__global__ __launch_bounds__(256) void prep(
    const float* __restrict__ x, const float* __restrict__ act_scale,
    const int* __restrict__ act_zp, char* __restrict__ xs,
    int* __restrict__ rowsum, int K, int M,
    const int4* __restrict__ wq, char4* __restrict__ wsq, long n4)
{
    if (blockIdx.x < (unsigned)M) {
        __shared__ int wsum[4];
        const int row = blockIdx.x;
        const float s = act_scale[0];
        const int zp = act_zp[0];
        const float4* __restrict__ xr = (const float4*)(x + (size_t)row * K);
        char4* __restrict__ xo = (char4*)(xs + (size_t)row * K);
        const int nv = K >> 2;
        int sum = 0;
        for (int i = threadIdx.x; i < nv; i += 256) {
            float4 v = xr[i];
            int q0 = min(max((int)rintf(v.x / s) + zp, 0), 255) - zp;
            int q1 = min(max((int)rintf(v.y / s) + zp, 0), 255) - zp;
            int q2 = min(max((int)rintf(v.z / s) + zp, 0), 255) - zp;
            int q3 = min(max((int)rintf(v.w / s) + zp, 0), 255) - zp;
            sum += q0 + q1 + q2 + q3;
            char4 c;
            c.x = (char)q0; c.y = (char)q1; c.z = (char)q2; c.w = (char)q3;
            xo[i] = c;
        }
        for (int off = 32; off > 0; off >>= 1) sum += __shfl_down(sum, off, 64);
        if ((threadIdx.x & 63) == 0) wsum[threadIdx.x >> 6] = sum;
        __syncthreads();
        if (threadIdx.x == 0) rowsum[row] = wsum[0] + wsum[1] + wsum[2] + wsum[3];
    } else {
        long i = (long)(blockIdx.x - M) * 256 + threadIdx.x;
        if (i >= n4) return;
        int4 v = wq[i];
        char4 c;
        c.x = (char)(v.x - 128); c.y = (char)(v.y - 128);
        c.z = (char)(v.z - 128); c.w = (char)(v.w - 128);
        wsq[i] = c;
    }
}

// ---------------------------------------------------------------------------
// Kernel 2: int8 GEMM, 256x256 tile, 8 waves (2M x 4N), BK=128 B.
//
// Deep-pipelined schedule (T3+T4+T5, depth fixed from round-1 post-mortem):
//   4 phases per K-tile, 16 MFMA each. Double-buffered LDS slots.
//   Staging units (each = 2 x global_load_lds x 512 threads):
//     B0 = B rows [0,128), B1 = [128,256),
//     A2 = A rows [0,64)u[128,192), A3 = [64,128)u[192,256).
//   Issue schedule (slot-liveness proven by the barrier chain):
//     tile T p0: issue T+1:A2,A3 into slot s^1  (4-phase depth)
//     tile T p2: issue T+2:B0,B1 into slot s    (6-phase depth ~1000cy > HBM)
//       (slot s's B region is dead after T p0's B-reads; s^1's A region is
//        dead after T-1 p3 — both guaranteed by the barrier at phase entry.)
//   Per-wave in-flight list at T p0 entry (oldest first):
//     [T:B0,B0',B1,B1' | T:A2,A2',A3,A3' | T+1:B0..B1'] = 12
//   Gates (counted, in-order vmcnt decrement => "complete N oldest"):
//     p0: vmcnt(6)  -> lands T:B0,B1,A2   (phases 0-1 read B + A2 rows)
//     p2: vmcnt(8)  -> lands T:A3         (phases 2-3 read A3 rows)
//   Tail peel (last tile): p0 vmcnt(2), p2 vmcnt(0). Requires NT>=2.
//   Raw s_barrier per phase; lgkmcnt(0)+sched_barrier(0) before MFMA cluster
//   (rule #18); setprio(1) around MFMAs (T5).
//
// LDS swizzle (conflict-free ds_read_b128): physical 16B chunk (row, pc)
// holds logical k-chunk c = pc ^ (row & 7); staging applies the swizzle on
// the per-lane GLOBAL source; readers XOR with (r&7).
__global__ __launch_bounds__(512, 2) void gemm_i8(
    const char* __restrict__ Aq, const char* __restrict__ Bq,
    const int* __restrict__ rowsum, const float* __restrict__ wscale,
    const int* __restrict__ wzp, const float* __restrict__ ascale,
    const float* __restrict__ bias, float* __restrict__ C,
    int M, int N, int K)
{
    __shared__ __align__(16) char As[2][BM * BKB];  // 2 x 32 KiB
    __shared__ __align__(16) char Bs[2][BN * BKB];  // 2 x 32 KiB

    const int tid = threadIdx.x;
    const int w   = tid >> 6;
    const int l   = tid & 63;

    // T1: bijective XCD swizzle (m204) — contiguous wg chunks per XCD
    const int nwg = gridDim.x;
    const int nbx = N / BN;
    const int orig = blockIdx.x;
    const int xcd = orig & 7;
    const int rest = orig >> 3;
    const int qq = nwg >> 3, rr = nwg & 7;
    const int wg = (xcd < rr ? xcd * (qq + 1) : rr * (qq + 1) + (xcd - rr) * qq)
                   + rest;
    const int n0 = (wg % nbx) * BN;
    const int m0 = (wg / nbx) * BM;

    const int wm = (w & 1) * 128;   // wave m-offset in tile
    const int wn = (w >> 1) * 64;   // wave n-offset in tile

    // ---- staging source (per-lane, pre-swizzled) + LDS unit bases (uniform)
    const int lr8 = l >> 3;
    const int csw = (((l & 7) ^ (lr8 & 7)) << 4);
    const int rB0 = w * 16;                                     // B-unit rows
    const int rA2 = (w < 4) ? (w * 16) : (128 + (w - 4) * 16);  // A2-unit rows

    const char* sB0 = Bq + (size_t)(n0 + rB0 + lr8) * K + csw;
    const char* sB1 = sB0 + (size_t)128 * K;
    const char* sA2 = Aq + (size_t)(m0 + rA2 + lr8) * K + csw;
    const char* sA3 = sA2 + (size_t)64 * K;
    const size_t k8 = (size_t)8 * K;

    const int oB0 = rB0 * BKB;
    const int oB1 = oB0 + 128 * BKB;
    const int oA2 = rA2 * BKB;
    const int oA3 = oA2 + 64 * BKB;

    // ---- fragment read offsets ----
    const int r   = l & 15;       // row within 16-tile (A: m, B: n)
    const int qk  = l >> 4;       // 16B k-quadrant within 64B k-slice
    const int rx  = r & 7;        // swizzle key
    const int rof = r * BKB;
    const int ck0 = ((qk ^ rx) << 4);
    const int ck1 = (((4 + qk) ^ rx) << 4);

    int32x4 acc[8][4] = {};
    const int NT = K / BKB;  // NT >= 2 assumed (K >= 256)

    // prologue — flight order MUST match steady state: T0:B, T0:A, T1:B
    load_lds16(sB0,      Bs[0] + oB0);
    load_lds16(sB0 + k8, Bs[0] + oB0 + 1024);
    load_lds16(sB1,      Bs[0] + oB1);
    load_lds16(sB1 + k8, Bs[0] + oB1 + 1024);
    load_lds16(sA2,      As[0] + oA2);
    load_lds16(sA2 + k8, As[0] + oA2 + 1024);
    load_lds16(sA3,      As[0] + oA3);
    load_lds16(sA3 + k8, As[0] + oA3 + 1024);
    if (NT > 1) {
        load_lds16(sB0 + BKB,      Bs[1] + oB0);
        load_lds16(sB0 + BKB + k8, Bs[1] + oB0 + 1024);
        load_lds16(sB1 + BKB,      Bs[1] + oB1);
        load_lds16(sB1 + BKB + k8, Bs[1] + oB1 + 1024);
    }
    sA2 += BKB; sA3 += BKB;                // next A issue: tile 1
    sB0 += 2 * (size_t)BKB; sB1 += 2 * (size_t)BKB;  // next B issue: tile 2

    int s = 0;
    for (int T = 0; T < NT; ++T) {
        const char* cA = As[s];
        const char* cB = Bs[s];
        char* nA = As[s ^ 1];
        char* nB = Bs[s];      // T+2's B lands in slot s (same parity as T)
        const bool stA = (T + 1 < NT);
        const bool stB = (T + 2 < NT);
        int32x4 bf[4][2];
#pragma unroll
        for (int p = 0; p < 4; ++p) {
            if (p == 0) { if (stA) { GATE(6); } else { GATE(2); } }
            if (p == 2) { if (stA) { GATE(8); } else { GATE(0); } }
            __builtin_amdgcn_s_barrier();

            // ds-reads for this phase (current tile, slot s)
            int32x4 af[2][2];
            const char* ab = cA + (wm + p * 32) * BKB + rof;
            af[0][0] = *(const int32x4*)(ab + ck0);
            af[0][1] = *(const int32x4*)(ab + ck1);
            af[1][0] = *(const int32x4*)(ab + 2048 + ck0);
            af[1][1] = *(const int32x4*)(ab + 2048 + ck1);
            if (p == 0) {
                const char* bb = cB + wn * BKB + rof;
#pragma unroll
                for (int j = 0; j < 4; ++j) {
                    bf[j][0] = *(const int32x4*)(bb + j * 2048 + ck0);
                    bf[j][1] = *(const int32x4*)(bb + j * 2048 + ck1);
                }
                if (stA) {  // issue T+1's A units -> slot s^1
                    load_lds16(sA2,      nA + oA2);
                    load_lds16(sA2 + k8, nA + oA2 + 1024);
                    load_lds16(sA3,      nA + oA3);
                    load_lds16(sA3 + k8, nA + oA3 + 1024);
                }
            }
            if (p == 2 && stB) {  // issue T+2's B units -> slot s
                load_lds16(sB0,      nB + oB0);
                load_lds16(sB0 + k8, nB + oB0 + 1024);
                load_lds16(sB1,      nB + oB1);
                load_lds16(sB1 + k8, nB + oB1 + 1024);
            }
            asm volatile("s_waitcnt lgkmcnt(0)" ::: "memory");
            __builtin_amdgcn_sched_barrier(0);
            __builtin_amdgcn_s_setprio(1);
#pragma unroll
            for (int i = 0; i < 2; ++i)
#pragma unroll
                for (int j = 0; j < 4; ++j) {
                    acc[p * 2 + i][j] = __builtin_amdgcn_mfma_i32_16x16x64_i8(
                        af[i][0], bf[j][0], acc[p * 2 + i][j], 0, 0, 0);
                    acc[p * 2 + i][j] = __builtin_amdgcn_mfma_i32_16x16x64_i8(
                        af[i][1], bf[j][1], acc[p * 2 + i][j], 0, 0, 0);
                }
            __builtin_amdgcn_s_setprio(0);
        }
        sA2 += BKB; sA3 += BKB; sB0 += BKB; sB1 += BKB;
        s ^= 1;
    }

    // epilogue: C/D layout col=lane&15, row=(lane>>4)*4+reg.
    // mkscales fused: alpha = a_s*w_s[n], beta = alpha*(128 - w_zp[n]).
    const float as = ascale[0];
    const int r4  = qk * 4;
    const int cil = r;
#pragma unroll
    for (int j = 0; j < 4; ++j) {
        const int col = n0 + wn + j * 16 + cil;
        const float al = as * wscale[col];
        const float be = al * (float)(128 - wzp[col]);
        const float bi = bias[col];
#pragma unroll
        for (int mi = 0; mi < 8; ++mi) {
            const int rowb = m0 + wm + mi * 16 + r4;
#pragma unroll
            for (int t = 0; t < 4; ++t) {
                const int row = rowb + t;
                C[(size_t)row * N + col] =
                    al * (float)acc[mi][j][t] + be * (float)rowsum[row] + bi;
            }
        }
    }
}

// ---------------------------------------------------------------------------
extern "C" void kernel_launch(void* const* d_in, const int* in_sizes, int n_in,
                              void* d_out, int out_size, void* d_ws, size_t ws_size,
                              hipStream_t stream) {
    const float* x      = (const float*)d_in[0];
    const int*   wq     = (const int*)d_in[1];
    const float* wscale = (const float*)d_in[2];
    const int*   wzp    = (const int*)d_in[3];
    const float* ascale = (const float*)d_in[4];
    const int*   azp    = (const int*)d_in[5];
    const float* bias   = (const float*)d_in[6];
    float* out = (float*)d_out;

    const int N = in_sizes[2];          // OUT
    const int K = in_sizes[1] / N;      // IN
    const int M = in_sizes[0] / K;      // B*S

    char* ws     = (char*)d_ws;
    char* xs     = ws;                                 // M*K int8
    char* wsq    = ws + (size_t)M * K;                 // N*K int8
    int*  rowsum = (int*)(wsq + (size_t)N * K);        // M int32

    long n4 = (long)N * K / 4;
    int wblocks = (int)((n4 + 255) / 256);
    prep<<<M + wblocks, 256, 0, stream>>>(
        x, ascale, azp, xs, rowsum, K, M, (const int4*)wq, (char4*)wsq, n4);

    dim3 grid((M / BM) * (N / BN));
    gemm_i8<<<grid, 512, 0, stream>>>(
        xs, wsq, rowsum, wscale, wzp, ascale, bias, out, M, N, K);
}